// Round 17
// baseline (165.986 us; speedup 1.0000x reference)
//
#include <hip/hip_runtime.h>
#include <math.h>
#include <stdint.h>

#define N_PIX 4096
#define CDIM 256
#define DINNER 512

typedef float vf4 __attribute__((ext_vector_type(4)));
typedef float f32x4 __attribute__((ext_vector_type(4)));
typedef float f32x16 __attribute__((ext_vector_type(16)));
typedef _Float16 half8 __attribute__((ext_vector_type(8)));
typedef _Float16 half4v __attribute__((ext_vector_type(4)));
typedef __fp16 fp16x2 __attribute__((ext_vector_type(2)));
typedef uint32_t u32x2 __attribute__((ext_vector_type(2)));
typedef uint32_t u32x4 __attribute__((ext_vector_type(4)));

#define LOG2E 1.44269504f
#define C1 0.36067376f           /* 0.25 * log2e */
#define EXP2(x) __builtin_amdgcn_exp2f(x)

#define GLOAD_LDS16(g, l)                                                  \
    __builtin_amdgcn_global_load_lds(                                      \
        (const __attribute__((address_space(1))) unsigned int*)(g),       \
        (__attribute__((address_space(3))) unsigned int*)(l), 16, 0, 0)

// ---------------------------------------------------------------------------
// Kernel 1 (fused prep): rnorm+fmapT16 / Wg16 / Wout16   (unchanged)
// ---------------------------------------------------------------------------
__global__ __launch_bounds__(256) void prep_kernel(
    const float* __restrict__ fmap, float* __restrict__ rnorm,
    _Float16* __restrict__ fmapT16,
    const float* __restrict__ Wq, const float* __restrict__ Wv,
    const float* __restrict__ gamma, const float* __restrict__ Wout,
    _Float16* __restrict__ Wg16, _Float16* __restrict__ Wout16) {
    const int t = threadIdx.x;
    if (blockIdx.x < 128) {
        __shared__ float red[4][64];
        const int pl = t & 63;
        const int part = t >> 6;
        const int pix0 = blockIdx.x * 64;
        const int gp = pix0 + pl;
        const int b = gp >> 12, p = gp & 4095;
        const float* f = fmap + ((size_t)b * CDIM + part * 64) * N_PIX + p;
        _Float16* o16 = fmapT16 + (size_t)gp * CDIM + part * 64;
        float s = 0.f;
        #pragma unroll
        for (int c8 = 0; c8 < 64; c8 += 8) {
            half8 hv;
            #pragma unroll
            for (int e = 0; e < 8; ++e) {
                float x = f[(size_t)(c8 + e) * N_PIX];
                s = fmaf(x, x, s);
                hv[e] = (_Float16)x;
            }
            *(half8*)(o16 + c8) = hv;
        }
        red[part][pl] = s;
        __syncthreads();
        if (t < 64) {
            float tot = red[0][t] + red[1][t] + red[2][t] + red[3][t];
            rnorm[pix0 + t] = 16.0f / fmaxf(sqrtf(tot), 1e-12f);
        }
    } else if (blockIdx.x < 384) {
        const int o = (blockIdx.x - 128) * 4 + (t >> 6);
        const int c = (t & 63) * 4;
        const float* W = (o < DINNER) ? (Wq + (size_t)o * CDIM)
                                      : (Wv + (size_t)(o - DINNER) * CDIM);
        vf4 wv = *(const vf4*)(W + c);
        vf4 gv = *(const vf4*)(gamma + c);
        half4v h = {(_Float16)(wv[0] * gv[0]), (_Float16)(wv[1] * gv[1]),
                    (_Float16)(wv[2] * gv[2]), (_Float16)(wv[3] * gv[3])};
        *(half4v*)(Wg16 + (size_t)o * CDIM + c) = h;
    } else {
        const int idx = ((blockIdx.x - 384) * 256 + t) * 4;
        vf4 wv = *(const vf4*)(Wout + idx);
        half4v h = {(_Float16)wv[0], (_Float16)wv[1], (_Float16)wv[2], (_Float16)wv[3]};
        *(half4v*)(Wout16 + idx) = h;
    }
}

// ---------------------------------------------------------------------------
// Kernel 2: fp16 MFMA projection GEMM.  NEW plane layouts for the 32x32 attn:
//  Kst[bh][tile][gi=d>>3][j][d&7] : element (j,d) at (d>>3)*512 + j*8 + (d&7)
//  Vst[bh][tile][gj=j>>3][d][j&7] : element (d,j) at (j>>3)*512 + d*8 + (j&7)
// cksq stores -0.5*qsq (from rounded fp16 q -> diag max exact).
// ---------------------------------------------------------------------------
__global__ __launch_bounds__(256) void proj_mfma(
    const _Float16* __restrict__ fmapT16,  // [b*4096+p][256]
    const _Float16* __restrict__ Wg16,     // [1024][256]
    const float* __restrict__ rnorm,       // [8192]
    _Float16* __restrict__ Kst, _Float16* __restrict__ Vst,
    float* __restrict__ cksq) {
    const int pt = blockIdx.x;             // 64
    const int mt = blockIdx.y;             // 16 (0..7 Q, 8..15 V)
    const int b = blockIdx.z;              // 2
    const int m0 = mt * 64;
    const bool isQ = (m0 < DINNER);
    const int h = (m0 & 511) >> 6;
    const int bh = b * 8 + h;
    const int p0 = pt * 64;

    const int t = threadIdx.x;
    const int w = t >> 6;
    const int lane = t & 63;
    const int col = lane & 15;
    const int g = lane >> 4;
    const int p = p0 + w * 16 + col;       // this lane's pixel
    const int j = w * 16 + col;            // pixel within the 64-tile

    const _Float16* bbase = fmapT16 + ((size_t)b * N_PIX + p) * CDIM;
    const _Float16* abase = Wg16 + (size_t)m0 * CDIM;

    f32x4 acc[4] = {};
    #pragma unroll
    for (int ks = 0; ks < 8; ++ks) {
        half8 bf = *(const half8*)(bbase + ks * 32 + g * 8);
        #pragma unroll
        for (int ms = 0; ms < 4; ++ms) {
            half8 af = *(const half8*)(abase + (size_t)(ms * 16 + col) * CDIM + ks * 32 + g * 8);
            acc[ms] = __builtin_amdgcn_mfma_f32_16x16x32_f16(af, bf, acc[ms], 0, 0, 0);
        }
    }

    const float rn = rnorm[b * N_PIX + p];
    _Float16 qh[4][4];
    #pragma unroll
    for (int ms = 0; ms < 4; ++ms)
        #pragma unroll
        for (int r = 0; r < 4; ++r)
            qh[ms][r] = (_Float16)(acc[ms][r] * rn);   // value at (d = ms*16+4g+r, pixel j)

    if (isQ) {
        float qs = 0.f;
        #pragma unroll
        for (int ms = 0; ms < 4; ++ms)
            #pragma unroll
            for (int r = 0; r < 4; ++r) {
                float qv = (float)qh[ms][r];
                qs = fmaf(qv, qv, qs);
            }
        qs += __shfl_xor(qs, 16);
        qs += __shfl_xor(qs, 32);
        _Float16* kt2 = Kst + ((size_t)bh * 64 + pt) * 4096;
        // (d>>3) = ms*2 + (g>>1); (d&7) = (g&1)*4 + r  -> r contiguous
        #pragma unroll
        for (int ms = 0; ms < 4; ++ms) {
            half4v hv = {qh[ms][0], qh[ms][1], qh[ms][2], qh[ms][3]};
            *(half4v*)(kt2 + (ms * 2 + (g >> 1)) * 512 + j * 8 + (g & 1) * 4) = hv;
        }
        if (g == 0)
            cksq[(size_t)bh * N_PIX + p] = -0.5f * qs;
    } else {
        _Float16* vt2 = Vst + ((size_t)bh * 64 + pt) * 4096;
        const int gj = j >> 3, je = j & 7;
        #pragma unroll
        for (int ms = 0; ms < 4; ++ms)
            #pragma unroll
            for (int r = 0; r < 4; ++r) {
                const int d = ms * 16 + 4 * g + r;
                vt2[gj * 512 + d * 8 + je] = qh[ms][r];
            }
    }
}

// ---------------------------------------------------------------------------
// Kernel 3: 32x32x16 MFMA flash attention, swapped QK^T.
// 8 waves: rg = w&3 (32 q-rows each), jh = w>>2 (32-j half).  Per tile:
// 4 QKT mfma (A=K plane frags) -> 16 exp2 -> pack + permlane32_swap -> 2x2
// PV mfma (A=V plane frags, B=P reassembled in-register).  jh partials
// combined via LDS at the end.  D-layout (m74/m101): col=lane&31,
// row=(reg&3)+8*(reg>>2)+4*(lane>>5).
// ---------------------------------------------------------------------------
__global__ __launch_bounds__(512, 4) void attn_kernel(
    const _Float16* __restrict__ Kst,  // [bh][tile][d>>3][j][d&7]
    const _Float16* __restrict__ Vst,  // [bh][tile][j>>3][d][j&7]
    const float* __restrict__ cksq,    // [bh][p] = -0.5*ksq
    const float* __restrict__ nullkv,  // [2][8][64] fp32
    _Float16* __restrict__ AO16)       // [b*4096+p][512]
{
    const int n = blockIdx.x;
    const int slot = n >> 3;
    const int bh = (n & 7) * 2 + (slot >> 5);   // XCD swizzle
    const int it = slot & 31;
    const int h = bh & 7;

    __shared__ __align__(16) _Float16 kv_lds[2][8192];  // [buf][K 4096 | V 4096]
    __shared__ float led[4][64][34];                    // [rg][lane][oacc 32, l]

    const int t = threadIdx.x;
    const int w = t >> 6;          // 0..7
    const int lane = t & 63;
    const int qcol = lane & 31;
    const int hi = lane >> 5;
    const int rg = w & 3, jh = w >> 2;

    const _Float16* kbase = Kst + (size_t)bh * (64 * 4096);
    const _Float16* vbase = Vst + (size_t)bh * (64 * 4096);
    const float* ck = cksq + (size_t)bh * N_PIX;
    const int i0 = it * 128 + rg * 32;
    const int qi = i0 + qcol;

    // prologue: stage tile 0 (wave w stages chunk w of K and of V)
    GLOAD_LDS16(kbase + w * 512 + lane * 8, &kv_lds[0][w * 512]);
    GLOAD_LDS16(vbase + w * 512 + lane * 8, &kv_lds[0][4096 + w * 512]);

    // Q fragments (B-operand): k-map d = dk*16 + hi*8 + e
    half8 qf[4];
    #pragma unroll
    for (int dk = 0; dk < 4; ++dk)
        qf[dk] = *(const half8*)(kbase + (size_t)(qi >> 6) * 4096 +
                                 (dk * 2 + hi) * 512 + (qi & 63) * 8);

    // null kv: per-lane partial over its 32 d, combined across hi
    float nd = 0.f, nkk = 0.f;
    #pragma unroll
    for (int dk = 0; dk < 4; ++dk) {
        const float* np = nullkv + h * 64 + dk * 16 + hi * 8;
        #pragma unroll
        for (int e = 0; e < 8; ++e) {
            float nkval = np[e];
            nkk = fmaf(nkval, nkval, nkk);
            nd = fmaf((float)qf[dk][e], nkval, nd);
        }
    }
    nd += __shfl_xor(nd, 32);
    nkk += __shfl_xor(nkk, 32);

    float m_, l_;
    f32x16 oacc[2];
    {
        float nsim = fmaf(0.25f, nd, -0.125f * nkk) * LOG2E;
        float ci = -C1 * ck[qi];
        m_ = fmaxf(ci, nsim);
        if (jh == 0) {
            float wn = EXP2(nsim - m_);
            l_ = 0.5f * wn;                 // summed over hi pair later
            #pragma unroll
            for (int dh = 0; dh < 2; ++dh)
                #pragma unroll
                for (int q = 0; q < 4; ++q) {
                    vf4 nv = *(const vf4*)(nullkv + DINNER + h * 64 + dh * 32 + q * 8 + hi * 4);
                    #pragma unroll
                    for (int rr = 0; rr < 4; ++rr)
                        oacc[dh][q * 4 + rr] = wn * nv[rr];
                }
        } else {
            l_ = 0.f;
            #pragma unroll
            for (int dh = 0; dh < 2; ++dh)
                #pragma unroll
                for (int rr = 0; rr < 16; ++rr)
                    oacc[dh][rr] = 0.f;
        }
    }
    const float nm = -m_;

    __syncthreads();   // tile 0 staged

    int cb = 0;
    #pragma unroll 1
    for (int jt64 = 0; jt64 < 64; ++jt64) {
        if (jt64 < 63) {
            GLOAD_LDS16(kbase + (size_t)(jt64 + 1) * 4096 + w * 512 + lane * 8,
                        &kv_lds[cb ^ 1][w * 512]);
            GLOAD_LDS16(vbase + (size_t)(jt64 + 1) * 4096 + w * 512 + lane * 8,
                        &kv_lds[cb ^ 1][4096 + w * 512]);
        }
        const _Float16* kl = &kv_lds[cb][0];
        const _Float16* vl = &kv_lds[cb][4096];
        const int j0 = jt64 * 64 + jh * 32;

        // S^T accumulator init = -0.5*ksq at j = j0 + (reg&3) + 8*(reg>>2) + 4*hi
        f32x16 sf;
        #pragma unroll
        for (int q = 0; q < 4; ++q) {
            vf4 c4 = *(const vf4*)&ck[j0 + q * 8 + hi * 4];
            #pragma unroll
            for (int rr = 0; rr < 4; ++rr)
                sf[q * 4 + rr] = c4[rr];
        }

        // QKT: A = K rows j (plane frags), B = Q
        __builtin_amdgcn_s_setprio(1);
        #pragma unroll
        for (int dk = 0; dk < 4; ++dk) {
            half8 kf = *(const half8*)(kl + (dk * 2 + hi) * 512 + (jh * 32 + qcol) * 8);
            sf = __builtin_amdgcn_mfma_f32_32x32x16_f16(kf, qf[dk], sf, 0, 0, 0);
        }
        __builtin_amdgcn_s_setprio(0);

        // softmax (m fixed) -> 16 exps -> pack -> permlane reassembly -> PV
        float ex[16];
        float ls = 0.f;
        #pragma unroll
        for (int rr = 0; rr < 16; ++rr) {
            ex[rr] = EXP2(fmaf(C1, sf[rr], nm));
            ls += ex[rr];
        }
        l_ += ls;

        #pragma unroll
        for (int c = 0; c < 2; ++c) {
            uint32_t a0 = __builtin_bit_cast(uint32_t, __builtin_amdgcn_cvt_pkrtz(ex[8 * c + 0], ex[8 * c + 1]));
            uint32_t a1 = __builtin_bit_cast(uint32_t, __builtin_amdgcn_cvt_pkrtz(ex[8 * c + 2], ex[8 * c + 3]));
            uint32_t b0 = __builtin_bit_cast(uint32_t, __builtin_amdgcn_cvt_pkrtz(ex[8 * c + 4], ex[8 * c + 5]));
            uint32_t b1 = __builtin_bit_cast(uint32_t, __builtin_amdgcn_cvt_pkrtz(ex[8 * c + 6], ex[8 * c + 7]));
            // v_permlane32_swap: new_dst.hi = src.lo, new_src.lo = dst.hi
            u32x2 s0 = __builtin_amdgcn_permlane32_swap(a0, b0, false, false);
            u32x2 s1 = __builtin_amdgcn_permlane32_swap(a1, b1, false, false);
            half8 pf = __builtin_bit_cast(half8, (u32x4){s0[0], s1[0], s0[1], s1[1]});
            __builtin_amdgcn_s_setprio(1);
            #pragma unroll
            for (int dh = 0; dh < 2; ++dh) {
                half8 vfrg = *(const half8*)(vl + (jh * 4 + c * 2 + hi) * 512 +
                                             (dh * 32 + qcol) * 8);
                oacc[dh] = __builtin_amdgcn_mfma_f32_32x32x16_f16(vfrg, pf, oacc[dh], 0, 0, 0);
            }
            __builtin_amdgcn_s_setprio(0);
        }

        __syncthreads();
        cb ^= 1;
    }

    // combine hi-pair l, then jh pair via LDS, normalize, store
    l_ += __shfl_xor(l_, 32);
    if (jh == 1) {
        #pragma unroll
        for (int dh = 0; dh < 2; ++dh)
            #pragma unroll
            for (int rr = 0; rr < 16; ++rr)
                led[rg][lane][dh * 16 + rr] = oacc[dh][rr];
        led[rg][lane][32] = l_;
    }
    __syncthreads();
    if (jh == 0) {
        l_ += led[rg][lane][32];
        float linv = 1.f / l_;
        _Float16* aop = AO16 + ((size_t)(bh >> 3) * N_PIX + qi) * DINNER + (h << 6);
        #pragma unroll
        for (int dh = 0; dh < 2; ++dh)
            #pragma unroll
            for (int q = 0; q < 4; ++q) {
                half4v hv;
                #pragma unroll
                for (int rr = 0; rr < 4; ++rr) {
                    float v = oacc[dh][q * 4 + rr] + led[rg][lane][dh * 16 + q * 4 + rr];
                    hv[rr] = (_Float16)(v * linv);
                }
                *(half4v*)(aop + dh * 32 + q * 8 + hi * 4) = hv;
            }
    }
}

// ---------------------------------------------------------------------------
// Kernel 4: fp16 MFMA output GEMM, split-K (unchanged from round 15)
// ---------------------------------------------------------------------------
__global__ __launch_bounds__(512) void outproj_mfma(
    const _Float16* __restrict__ AO16,    // [b*4096+p][512]
    const _Float16* __restrict__ Wout16,  // [256][512]
    float* __restrict__ out) {
    const int pt = blockIdx.x;   // 64
    const int mt = blockIdx.y;   // 4
    const int b = blockIdx.z;    // 2
    const int t = threadIdx.x;
    const int w = t >> 6, lane = t & 63, col = lane & 15, g = lane >> 4;
    const int wp = w & 3, wk = w >> 2;
    const int p = pt * 64 + wp * 16 + col;

    __shared__ f32x4 red[4][4][64];

    const _Float16* bbase = AO16 + ((size_t)b * N_PIX + p) * DINNER + wk * 256;
    const _Float16* abase = Wout16 + (size_t)(mt * 64) * DINNER + wk * 256;

    f32x4 acc[4] = {};
    #pragma unroll
    for (int ks = 0; ks < 8; ++ks) {
        half8 bf = *(const half8*)(bbase + ks * 32 + g * 8);
        #pragma unroll
        for (int ms = 0; ms < 4; ++ms) {
            half8 af = *(const half8*)(abase + (size_t)(ms * 16 + col) * DINNER + ks * 32 + g * 8);
            acc[ms] = __builtin_amdgcn_mfma_f32_16x16x32_f16(af, bf, acc[ms], 0, 0, 0);
        }
    }

    if (wk == 1) {
        #pragma unroll
        for (int ms = 0; ms < 4; ++ms)
            red[wp][ms][lane] = acc[ms];
    }
    __syncthreads();
    if (wk == 0) {
        float* ob = out + ((size_t)b * CDIM + mt * 64) * N_PIX + p;
        #pragma unroll
        for (int ms = 0; ms < 4; ++ms) {
            f32x4 s = acc[ms] + red[wp][ms][lane];
            #pragma unroll
            for (int r = 0; r < 4; ++r)
                ob[(size_t)(ms * 16 + 4 * g + r) * N_PIX] = s[r];
        }
    }
}

// ---------------------------------------------------------------------------
extern "C" void kernel_launch(void* const* d_in, const int* in_sizes, int n_in,
                              void* d_out, int out_size, void* d_ws, size_t ws_size,
                              hipStream_t stream) {
    const float* fmap   = (const float*)d_in[0];
    const float* gamma  = (const float*)d_in[1];
    const float* Wq     = (const float*)d_in[2];
    const float* Wv     = (const float*)d_in[3];
    const float* Wout   = (const float*)d_in[4];
    const float* nullkv = (const float*)d_in[5];
    float* out = (float*)d_out;

    char* wsb = (char*)d_ws;
    _Float16* Kst = (_Float16*)wsb;                          // 8 MB
    _Float16* Vst = (_Float16*)(wsb + (8u << 20));           // 8 MB
    _Float16* fmapT16 = (_Float16*)(wsb + (16u << 20));      // 4 MB (dead before AO16)
    _Float16* Wg16    = (_Float16*)(wsb + (20u << 20));      // 512 KB
    _Float16* AO16    = (_Float16*)(wsb + (16u << 20));      // 8 MB
    _Float16* Wout16  = (_Float16*)(wsb + (31u << 20));      // 256 KB
    float*    cksq    = (float*)(wsb + (32u << 20));         // 256 KB
    float*    rnorm   = (float*)(wsb + (33u << 20));         // 32 KB

    prep_kernel<<<512, 256, 0, stream>>>(fmap, rnorm, fmapT16,
                                         Wq, Wv, gamma, Wout, Wg16, Wout16);
    proj_mfma<<<dim3(64, 16, 2), 256, 0, stream>>>(fmapT16, Wg16, rnorm, Kst, Vst, cksq);
    attn_kernel<<<512, 512, 0, stream>>>(Kst, Vst, cksq, nullkv, AO16);
    outproj_mfma<<<dim3(64, 4, 2), 512, 0, stream>>>(AO16, Wout16, out);
}